// Round 4
// baseline (3037.569 us; speedup 1.0000x reference)
//
#include <hip/hip_runtime.h>
#include <stdint.h>

#define BATCH 4
#define NPTS  8192
#define CFEAT 64
#define MCENT 2048
#define NCENT (BATCH * MCENT)
#define KMAX  64
#define NEGV  -1e30f

// Exact-rounding squared distance, matching numpy's ((dx*dx+dy*dy)+dz*dz)
// with NO fma contraction (discrete neighbor selection requires bit parity).
__device__ __forceinline__ float dist2(float ax, float ay, float az,
                                       float bx, float by, float bz) {
    float dx = __fsub_rn(ax, bx);
    float dy = __fsub_rn(ay, by);
    float dz = __fsub_rn(az, bz);
    return __fadd_rn(__fadd_rn(__fmul_rn(dx, dx), __fmul_rn(dy, dy)),
                     __fmul_rn(dz, dz));
}

// DPP lane-permute helpers (VALU-latency cross-lane, vs ds_bpermute ~120cyc)
template <int CTRL>
__device__ __forceinline__ float dppf(float v) {
    return __int_as_float(__builtin_amdgcn_update_dpp(
        __float_as_int(v), __float_as_int(v), CTRL, 0xF, 0xF, false));
}
template <int CTRL>
__device__ __forceinline__ int dppi(int v) {
    return __builtin_amdgcn_update_dpp(v, v, CTRL, 0xF, 0xF, false);
}

// u64 max-combine with a DPP lane permute (lo/hi words permuted separately).
#define KSTEP(k, C_) { int klo_ = dppi<C_>((int)(unsigned int)(k));           \
                       int khi_ = dppi<C_>((int)(unsigned int)((k) >> 32));   \
                       unsigned long long ok_ =                               \
                           ((unsigned long long)(unsigned int)khi_ << 32) |   \
                           (unsigned int)klo_;                                \
                       (k) = ok_ > (k) ? ok_ : (k); }

// ---------------------------------------------------------------------------
// Kernel 1: farthest point sampling. One block per batch, 256 threads,
// 32 points per thread, all coords pinned in registers.
//
// Round-7 rationale: r3 counters show issue-bound (VALUBusy ~86% of the 4
// active CUs, ~1840 busy cy/iter) with per-WAVE overhead ~270 insts/iter.
// Total issue = dist(fixed/SIMD) + overhead*waves -> fewer fatter waves win.
// 256t/32-slot halves the overhead term vs 512t/16-slot. Tournament-tree
// argmax (depth 5) replaces the serial 32-step select chain so the single
// wave/SIMD doesn't expose a ~300cy dep chain. Wave tail: fused float-max
// absorb chain + readlane broadcast + int-min absorb chain (~2 insts/step)
// replaces u64 KSTEPs (5 insts/step). Cross-wave: 4 u64 key slots, 2-step
// butterfly. Exact semantics unchanged (max d2, tie -> min global index).
// ---------------------------------------------------------------------------
#define FPS_T   256
#define FPS_W   (FPS_T / 64)

#define REP32(X) X(0) X(1) X(2) X(3) X(4) X(5) X(6) X(7) \
                 X(8) X(9) X(10) X(11) X(12) X(13) X(14) X(15) \
                 X(16) X(17) X(18) X(19) X(20) X(21) X(22) X(23) \
                 X(24) X(25) X(26) X(27) X(28) X(29) X(30) X(31)

__global__ __launch_bounds__(FPS_T, 1) void fps_kernel(const float* __restrict__ pos,
                                                       float* __restrict__ pos_s) {
    const int b = blockIdx.x;
    const float* pb = pos + b * NPTS * 3;
    const int t = threadIdx.x;          // 0..255
    const int w = t >> 6;               // wave id 0..3
    const int lane = t & 63;

    __shared__ float2 sxy[NPTS];        // 64 KB (winner broadcast + writeback)
    __shared__ float  sz[NPTS];         // 32 KB
    __shared__ unsigned long long s_key[2][FPS_W];
    __shared__ int    s_win[MCENT];     // 8 KB winner indices

#define FPS_DECL(i) float px##i, py##i, pz##i, mind##i;
    REP32(FPS_DECL)
#undef FPS_DECL

    // load each point once: into pinned registers AND the LDS copy
#define FPS_LOAD(i) { int p = (i << 8) + t;                                   \
                      px##i = pb[3 * p + 0];                                  \
                      py##i = pb[3 * p + 1];                                  \
                      pz##i = pb[3 * p + 2];                                  \
                      float2 xy_; xy_.x = px##i; xy_.y = py##i;               \
                      sxy[p] = xy_;  sz[p] = pz##i;                           \
                      mind##i = 1e30f;                                        \
                      asm volatile("" : "+v"(px##i), "+v"(py##i), "+v"(pz##i)); }
    REP32(FPS_LOAD)
#undef FPS_LOAD

    if (t == 0) s_win[0] = 0;           // first centroid = point 0
    __syncthreads();

    float lx = sxy[0].x, ly = sxy[0].y, lz = sz[0];

    for (int m = 0; m < MCENT - 1; ++m) {
        // update mind (32 independent ops, full ILP)
#define FPS_UPD(i) { float d = dist2(px##i, py##i, pz##i, lx, ly, lz);        \
                     mind##i = fminf(mind##i, d); }
        REP32(FPS_UPD)
#undef FPS_UPD

        // tournament-tree argmax over the 32 slots. Strict >, left bias:
        // equal values keep the left (lower slot -> lower point index).
#define CMB(vo, io, va, ia, vb, ib)                                           \
        float vo; int io; { bool tk_ = (vb) > (va);                           \
                            vo = tk_ ? (vb) : (va);                           \
                            io = tk_ ? (ib) : (ia); }
        CMB(A0v,A0i,  mind0,0,   mind1,1)   CMB(A1v,A1i,  mind2,2,   mind3,3)
        CMB(A2v,A2i,  mind4,4,   mind5,5)   CMB(A3v,A3i,  mind6,6,   mind7,7)
        CMB(A4v,A4i,  mind8,8,   mind9,9)   CMB(A5v,A5i,  mind10,10, mind11,11)
        CMB(A6v,A6i,  mind12,12, mind13,13) CMB(A7v,A7i,  mind14,14, mind15,15)
        CMB(A8v,A8i,  mind16,16, mind17,17) CMB(A9v,A9i,  mind18,18, mind19,19)
        CMB(A10v,A10i,mind20,20, mind21,21) CMB(A11v,A11i,mind22,22, mind23,23)
        CMB(A12v,A12i,mind24,24, mind25,25) CMB(A13v,A13i,mind26,26, mind27,27)
        CMB(A14v,A14i,mind28,28, mind29,29) CMB(A15v,A15i,mind30,30, mind31,31)
        CMB(B0v,B0i, A0v,A0i,  A1v,A1i)   CMB(B1v,B1i, A2v,A2i,  A3v,A3i)
        CMB(B2v,B2i, A4v,A4i,  A5v,A5i)   CMB(B3v,B3i, A6v,A6i,  A7v,A7i)
        CMB(B4v,B4i, A8v,A8i,  A9v,A9i)   CMB(B5v,B5i, A10v,A10i,A11v,A11i)
        CMB(B6v,B6i, A12v,A12i,A13v,A13i) CMB(B7v,B7i, A14v,A14i,A15v,A15i)
        CMB(C0v,C0i, B0v,B0i, B1v,B1i)    CMB(C1v,C1i, B2v,B2i, B3v,B3i)
        CMB(C2v,C2i, B4v,B4i, B5v,B5i)    CMB(C3v,C3i, B6v,B6i, B7v,B7i)
        CMB(D0v,D0i, C0v,C0i, C1v,C1i)    CMB(D1v,D1i, C2v,C2i, C3v,C3i)
        CMB(E0v,E0i, D0v,D0i, D1v,D1i)
#undef CMB
        const float bv = E0v;
        const int   bp = (E0i << 8) + t;    // global point index

        // wave max via cheap fused-DPP fmax absorb chain -> lane 63
        float rv = bv;
        rv = fmaxf(rv, dppf<0xB1>(rv));
        rv = fmaxf(rv, dppf<0x4E>(rv));
        rv = fmaxf(rv, dppf<0x141>(rv));
        rv = fmaxf(rv, dppf<0x140>(rv));
        rv = fmaxf(rv, dppf<0x142>(rv));
        rv = fmaxf(rv, dppf<0x143>(rv));
        const float wmax = __int_as_float(
            __builtin_amdgcn_readlane(__float_as_int(rv), 63));

        // min global index among achievers (exact tie semantics)
        int cnd = (bv == wmax) ? bp : 0x7FFFFFFF;
        { int o;
          o = dppi<0xB1>(cnd);  cnd = o < cnd ? o : cnd;
          o = dppi<0x4E>(cnd);  cnd = o < cnd ? o : cnd;
          o = dppi<0x141>(cnd); cnd = o < cnd ? o : cnd;
          o = dppi<0x140>(cnd); cnd = o < cnd ? o : cnd;
          o = dppi<0x142>(cnd); cnd = o < cnd ? o : cnd;
          o = dppi<0x143>(cnd); cnd = o < cnd ? o : cnd; }

        const int par = m & 1;
        if (lane == 63) {
            unsigned long long key =
                ((unsigned long long)__float_as_uint(wmax) << 13) |
                (unsigned int)(8191 - cnd);
            s_key[par][w] = key;
        }
        __syncthreads();

        // cross-wave: 4 slots, 2-step u64 butterfly (period 4)
        unsigned long long k = s_key[par][t & 3];
        KSTEP(k, 0xB1)
        KSTEP(k, 0x4E)

        int gp = 8191 - (int)(k & 0x1FFFULL);
        if (t == 0) s_win[m + 1] = gp;
        float2 cxy = sxy[gp];            // broadcast LDS read (same addr)
        lx = cxy.x; ly = cxy.y; lz = sz[gp];
    }

    // bulk pos_s writeback (the only global stores in the kernel)
    __syncthreads();
    for (int m = t; m < MCENT; m += FPS_T) {
        int gp = s_win[m];
        float2 xy = sxy[gp]; float z = sz[gp];
        float* o = pos_s + (b * MCENT + m) * 3;
        o[0] = xy.x; o[1] = xy.y; o[2] = z;
    }
}
#undef KSTEP

// ---------------------------------------------------------------------------
// Kernel 2: exact top-64 (by (d2, idx) u64 key) within ball r=0.4 via
// histogram radix-select + O(C^2) exact ranking. Downstream max-aggregation
// is order-invariant, but ranks reproduce lax.top_k order anyway.
// ---------------------------------------------------------------------------
#define KNN_CAP 320

__global__ __launch_bounds__(256) void knn_kernel(const float* __restrict__ pos,
                                                  const float* __restrict__ pos_s,
                                                  int* __restrict__ nidx,
                                                  float* __restrict__ nd2,
                                                  int* __restrict__ ncnt) {
    const int c = blockIdx.x;
    const int b = c >> 11;              // c / MCENT
    const float* pb = pos + b * NPTS * 3;
    const int t = threadIdx.x;

    const float cx = pos_s[c * 3 + 0];
    const float cy = pos_s[c * 3 + 1];
    const float cz = pos_s[c * 3 + 2];

    __shared__ int hist[64];
    __shared__ int s_B64, s_total, s_cnt;
    __shared__ unsigned long long cand[KNN_CAP];

    if (t < 64) hist[t] = 0;
    if (t == 0) s_cnt = 0;
    __syncthreads();

    float d2r[32];
#pragma unroll
    for (int i = 0; i < 32; ++i) {
        int p = (i << 8) + t;
        float d2 = dist2(cx, cy, cz, pb[3 * p + 0], pb[3 * p + 1], pb[3 * p + 2]);
        d2r[i] = d2;
        if (d2 <= 0.16f) {
            int bkt = (int)(d2 * 400.0f);      // monotone; 0.16f*400 < 64
            bkt = bkt > 63 ? 63 : bkt;
            atomicAdd(&hist[bkt], 1);
        }
    }
    __syncthreads();

    if (t == 0) {
        int cum = 0, B = -1;
#pragma unroll
        for (int j = 0; j < 64; ++j) {
            cum += hist[j];
            if (B < 0 && cum >= 64) B = j;
        }
        s_B64 = (B < 0) ? 63 : B;
        s_total = cum;
    }
    __syncthreads();

    const int B64 = s_B64;
#pragma unroll
    for (int i = 0; i < 32; ++i) {
        float d2 = d2r[i];
        if (d2 <= 0.16f) {
            int bkt = (int)(d2 * 400.0f);
            bkt = bkt > 63 ? 63 : bkt;
            if (bkt <= B64) {
                int slot = atomicAdd(&s_cnt, 1);
                if (slot < KNN_CAP) {
                    int p = (i << 8) + t;
                    cand[slot] = ((unsigned long long)__float_as_uint(d2) << 32)
                                 | (unsigned int)p;
                }
            }
        }
    }
    __syncthreads();

    const int C = s_cnt < KNN_CAP ? s_cnt : KNN_CAP;
    // exact rank: candidate set is downward-closed, so candidate rank ==
    // global in-ball rank. Broadcast LDS reads (wave-uniform j).
    for (int tc = t; tc < C; tc += 256) {
        unsigned long long my = cand[tc];
        int rank = 0;
        for (int j = 0; j < C; ++j) rank += (cand[j] < my) ? 1 : 0;
        if (rank < KMAX) {
            nidx[c * KMAX + rank] = (int)(my & 0xffffffffULL);
            nd2[c * KMAX + rank]  = __uint_as_float((unsigned int)(my >> 32));
        }
    }
    if (t == 0) ncnt[c] = s_total < KMAX ? s_total : KMAX;
}

// ---------------------------------------------------------------------------
// Kernel 3: fused gather + 2-layer MLP + masked max per centroid.
//
// Round-7: the C2==256 instantiation's old layer 2 cached w2c[C1=128] per
// thread -> cannot be VGPR-resident (rocprof: VGPR_Count=84) -> W2 reloaded
// per use (8192 loads/thread). New layer 2: k-split across the 4 waves
// (16 k-rows each), 4 j-columns per lane; acc[16][4] statically indexed in
// registers; W2 read once via dwordx4; H read once per wave as broadcast
// ds_read_b128. FP op order per (k,j) is bit-identical; k-max reassociation
// is exact (fmax is truly associative).
// ---------------------------------------------------------------------------
template <int K, int C1, int C2, int OUTOFF>
__global__ __launch_bounds__(256, 2) void mlp_kernel(
        const float* __restrict__ x, const float* __restrict__ pos,
        const float* __restrict__ pos_s,
        const int* __restrict__ nidx, const float* __restrict__ nd2,
        const int* __restrict__ ncnt,
        const float* __restrict__ W1, const float* __restrict__ B1,
        const float* __restrict__ W2, const float* __restrict__ B2,
        float* __restrict__ out, float r2) {
    const int c = blockIdx.x;
    const int b = c >> 11;
    const int t = threadIdx.x;

    __shared__ float F[K][68];      // [K][67] padded to 17 float4
    __shared__ float H[K][C1];
    __shared__ int   s_nbr[K];
    __shared__ int   s_valid[K];
    __shared__ float s_ctr[3];

    const int cntAll = ncnt[c];
    const int cnt = cntAll < K ? cntAll : K;
    if (t < 3) s_ctr[t] = pos_s[c * 3 + t];
    if (t < K) {
        bool ok = t < cnt;
        s_nbr[t]   = ok ? nidx[c * KMAX + t] : 0;
        s_valid[t] = ok && (nd2[c * KMAX + t] <= r2);
    }
    __syncthreads();

    // gather features: F[k] = [ x[nbr] (64) | pos[nbr]-ctr (3) | 0 pad ]
    for (int e = t; e < K * 17; e += 256) {
        int k = e / 17, q = e % 17;
        int nbr = s_nbr[k];
        bool ok = k < cnt;
        float4 val;
        if (q < 16) {
            const float4* xr = (const float4*)(x + (b * NPTS + nbr) * CFEAT);
            if (ok) val = xr[q];
            else { val.x = 0.f; val.y = 0.f; val.z = 0.f; val.w = 0.f; }
        } else {
            const float* pp = pos + (b * NPTS + nbr) * 3;
            val.x = ok ? pp[0] - s_ctr[0] : 0.f;
            val.y = ok ? pp[1] - s_ctr[1] : 0.f;
            val.z = ok ? pp[2] - s_ctr[2] : 0.f;
            val.w = 0.f;
        }
        ((float4*)&F[k][0])[q] = val;
    }
    __syncthreads();

    // layer 1: H[k][j] = relu(B1[j] + F[k]·W1[:,j])
    {
        constexpr int STR = 256 / C1;
        const int j  = t % C1;
        const int kb = t / C1;
        float w1c[68];
#pragma unroll
        for (int i = 0; i < 67; ++i) w1c[i] = W1[i * C1 + j];
        w1c[67] = 0.f;
        const float bj = B1[j];
        for (int k = kb; k < K; k += STR) {
            float acc = bj;
            const float4* fr = (const float4*)&F[k][0];
#pragma unroll
            for (int q = 0; q < 17; ++q) {
                float4 f = fr[q];
                acc = fmaf(f.x, w1c[4 * q + 0], acc);
                acc = fmaf(f.y, w1c[4 * q + 1], acc);
                acc = fmaf(f.z, w1c[4 * q + 2], acc);
                acc = fmaf(f.w, w1c[4 * q + 3], acc);
            }
            H[k][j] = fmaxf(acc, 0.f);
        }
    }
    __syncthreads();

    // layer 2 + masked max over neighbors
    if constexpr (C2 == 256) {
        // k-split across waves; 4 j columns per lane; acc in registers.
        const int lane_ = t & 63;
        const int wv_   = t >> 6;           // 0..3
        const int j0    = lane_ * 4;
        const int k0    = wv_ * (K / 4);    // 16 k-rows per wave
        float4 bjv = *(const float4*)&B2[j0];
        float acc[K / 4][4];
#pragma unroll
        for (int kk = 0; kk < K / 4; ++kk) {
            acc[kk][0] = bjv.x; acc[kk][1] = bjv.y;
            acc[kk][2] = bjv.z; acc[kk][3] = bjv.w;
        }
        for (int i = 0; i < C1; i += 4) {
            float4 w0 = *(const float4*)&W2[(i + 0) * C2 + j0];
            float4 w1 = *(const float4*)&W2[(i + 1) * C2 + j0];
            float4 w2 = *(const float4*)&W2[(i + 2) * C2 + j0];
            float4 w3 = *(const float4*)&W2[(i + 3) * C2 + j0];
#pragma unroll
            for (int kk = 0; kk < K / 4; ++kk) {
                float4 h = *(const float4*)&H[k0 + kk][i];   // broadcast
                acc[kk][0] = fmaf(h.x, w0.x, acc[kk][0]);
                acc[kk][0] = fmaf(h.y, w1.x, acc[kk][0]);
                acc[kk][0] = fmaf(h.z, w2.x, acc[kk][0]);
                acc[kk][0] = fmaf(h.w, w3.x, acc[kk][0]);
                acc[kk][1] = fmaf(h.x, w0.y, acc[kk][1]);
                acc[kk][1] = fmaf(h.y, w1.y, acc[kk][1]);
                acc[kk][1] = fmaf(h.z, w2.y, acc[kk][1]);
                acc[kk][1] = fmaf(h.w, w3.y, acc[kk][1]);
                acc[kk][2] = fmaf(h.x, w0.z, acc[kk][2]);
                acc[kk][2] = fmaf(h.y, w1.z, acc[kk][2]);
                acc[kk][2] = fmaf(h.z, w2.z, acc[kk][2]);
                acc[kk][2] = fmaf(h.w, w3.z, acc[kk][2]);
                acc[kk][3] = fmaf(h.x, w0.w, acc[kk][3]);
                acc[kk][3] = fmaf(h.y, w1.w, acc[kk][3]);
                acc[kk][3] = fmaf(h.z, w2.w, acc[kk][3]);
                acc[kk][3] = fmaf(h.w, w3.w, acc[kk][3]);
            }
        }
        __shared__ float pm2[4][C2];
        float m0 = NEGV, m1 = NEGV, m2 = NEGV, m3 = NEGV;
#pragma unroll
        for (int kk = 0; kk < K / 4; ++kk) {
            if (s_valid[k0 + kk]) {         // wave-uniform branch
                m0 = fmaxf(m0, fmaxf(acc[kk][0], 0.f));
                m1 = fmaxf(m1, fmaxf(acc[kk][1], 0.f));
                m2 = fmaxf(m2, fmaxf(acc[kk][2], 0.f));
                m3 = fmaxf(m3, fmaxf(acc[kk][3], 0.f));
            }
        }
        float4 mv; mv.x = m0; mv.y = m1; mv.z = m2; mv.w = m3;
        *(float4*)&pm2[wv_][j0] = mv;
        __syncthreads();
        float r = fmaxf(fmaxf(pm2[0][t], pm2[1][t]),
                        fmaxf(pm2[2][t], pm2[3][t]));
        out[c * 384 + OUTOFF + t] = r;
    } else {
        // C2 == 128: 2 thread-groups split the k range, combine via LDS
        const int j2 = t % C2;
        const int g  = t / C2;
        __shared__ float pm[256];
        float w2c[C1];
#pragma unroll
        for (int i = 0; i < C1; ++i) w2c[i] = W2[i * C2 + j2];
        const float bj = B2[j2];
        float omax = NEGV;
        for (int k = g; k < K; k += 2) {
            if (!s_valid[k]) continue;
            float acc = bj;
            const float4* hr = (const float4*)&H[k][0];
#pragma unroll
            for (int q = 0; q < C1 / 4; ++q) {
                float4 h = hr[q];
                acc = fmaf(h.x, w2c[4 * q + 0], acc);
                acc = fmaf(h.y, w2c[4 * q + 1], acc);
                acc = fmaf(h.z, w2c[4 * q + 2], acc);
                acc = fmaf(h.w, w2c[4 * q + 3], acc);
            }
            omax = fmaxf(omax, fmaxf(acc, 0.f));
        }
        pm[t] = omax;
        __syncthreads();
        if (t < C2) out[c * 384 + OUTOFF + t] = fmaxf(pm[t], pm[t + C2]);
    }
}

extern "C" void kernel_launch(void* const* d_in, const int* in_sizes, int n_in,
                              void* d_out, int out_size, void* d_ws, size_t ws_size,
                              hipStream_t stream) {
    const float* x    = (const float*)d_in[0];
    const float* pos  = (const float*)d_in[1];
    const float* w1_0 = (const float*)d_in[2];
    const float* b1_0 = (const float*)d_in[3];
    const float* w1_1 = (const float*)d_in[4];
    const float* b1_1 = (const float*)d_in[5];
    const float* w2_0 = (const float*)d_in[6];
    const float* b2_0 = (const float*)d_in[7];
    const float* w2_1 = (const float*)d_in[8];
    const float* b2_1 = (const float*)d_in[9];

    float* out   = (float*)d_out;
    float* pos_s = out + NCENT * 384;          // second output, written by FPS

    char* ws = (char*)d_ws;
    int*   ncnt = (int*)ws;                                   // NCENT ints
    int*   nidx = (int*)(ws + NCENT * 4);                     // NCENT*64 ints
    float* nd2  = (float*)(ws + NCENT * 4 + NCENT * KMAX * 4);// NCENT*64 floats

    fps_kernel<<<BATCH, FPS_T, 0, stream>>>(pos, pos_s);
    knn_kernel<<<NCENT, 256, 0, stream>>>(pos, pos_s, nidx, nd2, ncnt);
    mlp_kernel<32, 64, 128, 0><<<NCENT, 256, 0, stream>>>(
        x, pos, pos_s, nidx, nd2, ncnt, w1_0, b1_0, w1_1, b1_1, out, 0.04f);
    mlp_kernel<64, 128, 256, 128><<<NCENT, 256, 0, stream>>>(
        x, pos, pos_s, nidx, nd2, ncnt, w2_0, b2_0, w2_1, b2_1, out, 0.16f);
}

// Round 5
// 2968.921 us; speedup vs baseline: 1.0231x; 1.0231x over previous
//
#include <hip/hip_runtime.h>
#include <stdint.h>

#define BATCH 4
#define NPTS  8192
#define CFEAT 64
#define MCENT 2048
#define NCENT (BATCH * MCENT)
#define KMAX  64
#define NEGV  -1e30f

// Exact-rounding squared distance, matching numpy's ((dx*dx+dy*dy)+dz*dz)
// with NO fma contraction (discrete neighbor selection requires bit parity).
__device__ __forceinline__ float dist2(float ax, float ay, float az,
                                       float bx, float by, float bz) {
    float dx = __fsub_rn(ax, bx);
    float dy = __fsub_rn(ay, by);
    float dz = __fsub_rn(az, bz);
    return __fadd_rn(__fadd_rn(__fmul_rn(dx, dx), __fmul_rn(dy, dy)),
                     __fmul_rn(dz, dz));
}

// DPP lane-permute helpers (VALU-latency cross-lane, vs ds_bpermute ~120cyc)
template <int CTRL>
__device__ __forceinline__ float dppf(float v) {
    return __int_as_float(__builtin_amdgcn_update_dpp(
        __float_as_int(v), __float_as_int(v), CTRL, 0xF, 0xF, false));
}
template <int CTRL>
__device__ __forceinline__ int dppi(int v) {
    return __builtin_amdgcn_update_dpp(v, v, CTRL, 0xF, 0xF, false);
}

// ---------------------------------------------------------------------------
// Kernel 1: farthest point sampling. One block per batch, 512 threads
// (2 waves/SIMD — r4 showed 1 wave/SIMD exposes VALU latency), 16 points
// per thread, all coords pinned in registers.
//
// Round-8 tail restructure: index tracking removed from the hot reduction.
//  - updates: 16x (dist2 + fmin), no select chains
//  - thread max: float-only v_max3-fusible tree
//  - wave max: 6-step fmax DPP absorb; cross-wave: 8 LDS floats + 3-step
//    butterfly (xor1/xor2/xor7) -> gmax in all lanes
//  - index recovery RARE PATH: threads with bv == gmax (exact: fmax is a
//    bit-selection on nonneg floats, so an achiever always exists) scan
//    their 16 slots and atomicMax a tagged key ((m+1)<<13 | 8191-li) into
//    ONE LDS word. Monotone tag -> no reset, no parity, still 2 barriers.
//    Max-of-key == (max d2, tie -> min global index) exactly.
// ---------------------------------------------------------------------------
#define FPS_T   512
#define FPS_W   (FPS_T / 64)

#define REP16(X) X(0) X(1) X(2) X(3) X(4) X(5) X(6) X(7) \
                 X(8) X(9) X(10) X(11) X(12) X(13) X(14) X(15)

__global__ __launch_bounds__(FPS_T, 1) void fps_kernel(const float* __restrict__ pos,
                                                       float* __restrict__ pos_s) {
    const int b = blockIdx.x;
    const float* pb = pos + b * NPTS * 3;
    const int t = threadIdx.x;          // 0..511
    const int w = t >> 6;               // wave id 0..7
    const int lane = t & 63;

    __shared__ float2 sxy[NPTS];        // 64 KB (winner broadcast + writeback)
    __shared__ float  sz[NPTS];         // 32 KB
    __shared__ float  s_red[FPS_W];     // per-wave maxima (no parity needed)
    __shared__ int    s_wkey;           // tagged winner key (monotone in m)
    __shared__ int    s_win[MCENT];     // 8 KB winner indices

#define FPS_DECL(i) float px##i, py##i, pz##i, mind##i;
    REP16(FPS_DECL)
#undef FPS_DECL

    // load each point once: into pinned registers AND the LDS copy
#define FPS_LOAD(i) { int p = (i << 9) + t;                                   \
                      px##i = pb[3 * p + 0];                                  \
                      py##i = pb[3 * p + 1];                                  \
                      pz##i = pb[3 * p + 2];                                  \
                      float2 xy_; xy_.x = px##i; xy_.y = py##i;               \
                      sxy[p] = xy_;  sz[p] = pz##i;                           \
                      mind##i = 1e30f;                                        \
                      asm volatile("" : "+v"(px##i), "+v"(py##i), "+v"(pz##i)); }
    REP16(FPS_LOAD)
#undef FPS_LOAD

    if (t == 0) { s_win[0] = 0; s_wkey = 0; }   // first centroid = point 0
    __syncthreads();

    float lx = sxy[0].x, ly = sxy[0].y, lz = sz[0];

    for (int m = 0; m < MCENT - 1; ++m) {
        // update mind (16 independent fmin chains, full ILP, no index sel)
#define FPS_UPD(i) { float d = dist2(px##i, py##i, pz##i, lx, ly, lz);        \
                     mind##i = fminf(mind##i, d); }
        REP16(FPS_UPD)
#undef FPS_UPD

        // thread-local float max: v_max3-fusible tree (no index tracking)
        float r0 = fmaxf(fmaxf(mind0,  mind1),  mind2);
        float r1 = fmaxf(fmaxf(mind3,  mind4),  mind5);
        float r2 = fmaxf(fmaxf(mind6,  mind7),  mind8);
        float r3 = fmaxf(fmaxf(mind9,  mind10), mind11);
        float r4 = fmaxf(fmaxf(mind12, mind13), mind14);
        float s0 = fmaxf(fmaxf(r0, r1), r2);
        float s1 = fmaxf(fmaxf(r3, r4), mind15);
        const float bv = fmaxf(s0, s1);

        // wave fmax absorb chain -> lane 63 holds the wave max
        float rv = bv;
        rv = fmaxf(rv, dppf<0xB1>(rv));     // xor1
        rv = fmaxf(rv, dppf<0x4E>(rv));     // xor2
        rv = fmaxf(rv, dppf<0x141>(rv));    // xor4 (row_half_mirror)
        rv = fmaxf(rv, dppf<0x140>(rv));    // xor8 (row_mirror)
        rv = fmaxf(rv, dppf<0x142>(rv));    // row_bcast15
        rv = fmaxf(rv, dppf<0x143>(rv));    // row_bcast31
        if (lane == 63) s_red[w] = rv;
        __syncthreads();

        // cross-wave: 8 slots -> 3-step DPP butterfly (xor1, xor2, xor7)
        float g = s_red[t & 7];
        g = fmaxf(g, dppf<0xB1>(g));
        g = fmaxf(g, dppf<0x4E>(g));
        g = fmaxf(g, dppf<0x141>(g));       // half-row mirror == xor7 on 3 bits
        // g == global max in every lane

        // RARE PATH: achiever threads recover min local index and publish.
        if (bv == g) {
            int li = 0x7FFFFFFF;
#define FPS_SCAN(i) { int p_ = (i << 9) + t;                                  \
                      int cand_ = (mind##i == g) ? p_ : 0x7FFFFFFF;           \
                      li = cand_ < li ? cand_ : li; }
            REP16(FPS_SCAN)
#undef FPS_SCAN
            atomicMax(&s_wkey, (int)(((m + 1) << 13) | (8191 - li)));
        }
        __syncthreads();

        // tag is guaranteed current (>=1 achiever wrote; tag dominates key)
        const int gp = 8191 - (s_wkey & 0x1FFF);
        if (t == 0) s_win[m + 1] = gp;
        float2 cxy = sxy[gp];               // broadcast LDS read (same addr)
        lx = cxy.x; ly = cxy.y; lz = sz[gp];
    }

    // bulk pos_s writeback (the only global stores in the kernel)
    __syncthreads();
    for (int m = t; m < MCENT; m += FPS_T) {
        int gp = s_win[m];
        float2 xy = sxy[gp]; float z = sz[gp];
        float* o = pos_s + (b * MCENT + m) * 3;
        o[0] = xy.x; o[1] = xy.y; o[2] = z;
    }
}

// ---------------------------------------------------------------------------
// Kernel 2: exact top-64 (by (d2, idx) u64 key) within ball r=0.4 via
// histogram radix-select + O(C^2) exact ranking. Downstream max-aggregation
// is order-invariant, but ranks reproduce lax.top_k order anyway.
// ---------------------------------------------------------------------------
#define KNN_CAP 320

__global__ __launch_bounds__(256) void knn_kernel(const float* __restrict__ pos,
                                                  const float* __restrict__ pos_s,
                                                  int* __restrict__ nidx,
                                                  float* __restrict__ nd2,
                                                  int* __restrict__ ncnt) {
    const int c = blockIdx.x;
    const int b = c >> 11;              // c / MCENT
    const float* pb = pos + b * NPTS * 3;
    const int t = threadIdx.x;

    const float cx = pos_s[c * 3 + 0];
    const float cy = pos_s[c * 3 + 1];
    const float cz = pos_s[c * 3 + 2];

    __shared__ int hist[64];
    __shared__ int s_B64, s_total, s_cnt;
    __shared__ unsigned long long cand[KNN_CAP];

    if (t < 64) hist[t] = 0;
    if (t == 0) s_cnt = 0;
    __syncthreads();

    float d2r[32];
#pragma unroll
    for (int i = 0; i < 32; ++i) {
        int p = (i << 8) + t;
        float d2 = dist2(cx, cy, cz, pb[3 * p + 0], pb[3 * p + 1], pb[3 * p + 2]);
        d2r[i] = d2;
        if (d2 <= 0.16f) {
            int bkt = (int)(d2 * 400.0f);      // monotone; 0.16f*400 < 64
            bkt = bkt > 63 ? 63 : bkt;
            atomicAdd(&hist[bkt], 1);
        }
    }
    __syncthreads();

    if (t == 0) {
        int cum = 0, B = -1;
#pragma unroll
        for (int j = 0; j < 64; ++j) {
            cum += hist[j];
            if (B < 0 && cum >= 64) B = j;
        }
        s_B64 = (B < 0) ? 63 : B;
        s_total = cum;
    }
    __syncthreads();

    const int B64 = s_B64;
#pragma unroll
    for (int i = 0; i < 32; ++i) {
        float d2 = d2r[i];
        if (d2 <= 0.16f) {
            int bkt = (int)(d2 * 400.0f);
            bkt = bkt > 63 ? 63 : bkt;
            if (bkt <= B64) {
                int slot = atomicAdd(&s_cnt, 1);
                if (slot < KNN_CAP) {
                    int p = (i << 8) + t;
                    cand[slot] = ((unsigned long long)__float_as_uint(d2) << 32)
                                 | (unsigned int)p;
                }
            }
        }
    }
    __syncthreads();

    const int C = s_cnt < KNN_CAP ? s_cnt : KNN_CAP;
    // exact rank: candidate set is downward-closed, so candidate rank ==
    // global in-ball rank. Broadcast LDS reads (wave-uniform j).
    for (int tc = t; tc < C; tc += 256) {
        unsigned long long my = cand[tc];
        int rank = 0;
        for (int j = 0; j < C; ++j) rank += (cand[j] < my) ? 1 : 0;
        if (rank < KMAX) {
            nidx[c * KMAX + rank] = (int)(my & 0xffffffffULL);
            nd2[c * KMAX + rank]  = __uint_as_float((unsigned int)(my >> 32));
        }
    }
    if (t == 0) ncnt[c] = s_total < KMAX ? s_total : KMAX;
}

// ---------------------------------------------------------------------------
// Kernel 3: fused gather + 2-layer MLP + masked max per centroid.
//
// r4: C2==256 layer 2 is a k-split register-tiled GEMM (waves own 16 k-rows,
// lanes own 4 j-cols, acc statically indexed). Kept unchanged this round.
// ---------------------------------------------------------------------------
template <int K, int C1, int C2, int OUTOFF>
__global__ __launch_bounds__(256, 2) void mlp_kernel(
        const float* __restrict__ x, const float* __restrict__ pos,
        const float* __restrict__ pos_s,
        const int* __restrict__ nidx, const float* __restrict__ nd2,
        const int* __restrict__ ncnt,
        const float* __restrict__ W1, const float* __restrict__ B1,
        const float* __restrict__ W2, const float* __restrict__ B2,
        float* __restrict__ out, float r2) {
    const int c = blockIdx.x;
    const int b = c >> 11;
    const int t = threadIdx.x;

    __shared__ float F[K][68];      // [K][67] padded to 17 float4
    __shared__ float H[K][C1];
    __shared__ int   s_nbr[K];
    __shared__ int   s_valid[K];
    __shared__ float s_ctr[3];

    const int cntAll = ncnt[c];
    const int cnt = cntAll < K ? cntAll : K;
    if (t < 3) s_ctr[t] = pos_s[c * 3 + t];
    if (t < K) {
        bool ok = t < cnt;
        s_nbr[t]   = ok ? nidx[c * KMAX + t] : 0;
        s_valid[t] = ok && (nd2[c * KMAX + t] <= r2);
    }
    __syncthreads();

    // gather features: F[k] = [ x[nbr] (64) | pos[nbr]-ctr (3) | 0 pad ]
    for (int e = t; e < K * 17; e += 256) {
        int k = e / 17, q = e % 17;
        int nbr = s_nbr[k];
        bool ok = k < cnt;
        float4 val;
        if (q < 16) {
            const float4* xr = (const float4*)(x + (b * NPTS + nbr) * CFEAT);
            if (ok) val = xr[q];
            else { val.x = 0.f; val.y = 0.f; val.z = 0.f; val.w = 0.f; }
        } else {
            const float* pp = pos + (b * NPTS + nbr) * 3;
            val.x = ok ? pp[0] - s_ctr[0] : 0.f;
            val.y = ok ? pp[1] - s_ctr[1] : 0.f;
            val.z = ok ? pp[2] - s_ctr[2] : 0.f;
            val.w = 0.f;
        }
        ((float4*)&F[k][0])[q] = val;
    }
    __syncthreads();

    // layer 1: H[k][j] = relu(B1[j] + F[k]·W1[:,j])
    {
        constexpr int STR = 256 / C1;
        const int j  = t % C1;
        const int kb = t / C1;
        float w1c[68];
#pragma unroll
        for (int i = 0; i < 67; ++i) w1c[i] = W1[i * C1 + j];
        w1c[67] = 0.f;
        const float bj = B1[j];
        for (int k = kb; k < K; k += STR) {
            float acc = bj;
            const float4* fr = (const float4*)&F[k][0];
#pragma unroll
            for (int q = 0; q < 17; ++q) {
                float4 f = fr[q];
                acc = fmaf(f.x, w1c[4 * q + 0], acc);
                acc = fmaf(f.y, w1c[4 * q + 1], acc);
                acc = fmaf(f.z, w1c[4 * q + 2], acc);
                acc = fmaf(f.w, w1c[4 * q + 3], acc);
            }
            H[k][j] = fmaxf(acc, 0.f);
        }
    }
    __syncthreads();

    // layer 2 + masked max over neighbors
    if constexpr (C2 == 256) {
        // k-split across waves; 4 j columns per lane; acc in registers.
        const int lane_ = t & 63;
        const int wv_   = t >> 6;           // 0..3
        const int j0    = lane_ * 4;
        const int k0    = wv_ * (K / 4);    // 16 k-rows per wave
        float4 bjv = *(const float4*)&B2[j0];
        float acc[K / 4][4];
#pragma unroll
        for (int kk = 0; kk < K / 4; ++kk) {
            acc[kk][0] = bjv.x; acc[kk][1] = bjv.y;
            acc[kk][2] = bjv.z; acc[kk][3] = bjv.w;
        }
        for (int i = 0; i < C1; i += 4) {
            float4 w0 = *(const float4*)&W2[(i + 0) * C2 + j0];
            float4 w1 = *(const float4*)&W2[(i + 1) * C2 + j0];
            float4 w2 = *(const float4*)&W2[(i + 2) * C2 + j0];
            float4 w3 = *(const float4*)&W2[(i + 3) * C2 + j0];
#pragma unroll
            for (int kk = 0; kk < K / 4; ++kk) {
                float4 h = *(const float4*)&H[k0 + kk][i];   // broadcast
                acc[kk][0] = fmaf(h.x, w0.x, acc[kk][0]);
                acc[kk][0] = fmaf(h.y, w1.x, acc[kk][0]);
                acc[kk][0] = fmaf(h.z, w2.x, acc[kk][0]);
                acc[kk][0] = fmaf(h.w, w3.x, acc[kk][0]);
                acc[kk][1] = fmaf(h.x, w0.y, acc[kk][1]);
                acc[kk][1] = fmaf(h.y, w1.y, acc[kk][1]);
                acc[kk][1] = fmaf(h.z, w2.y, acc[kk][1]);
                acc[kk][1] = fmaf(h.w, w3.y, acc[kk][1]);
                acc[kk][2] = fmaf(h.x, w0.z, acc[kk][2]);
                acc[kk][2] = fmaf(h.y, w1.z, acc[kk][2]);
                acc[kk][2] = fmaf(h.z, w2.z, acc[kk][2]);
                acc[kk][2] = fmaf(h.w, w3.z, acc[kk][2]);
                acc[kk][3] = fmaf(h.x, w0.w, acc[kk][3]);
                acc[kk][3] = fmaf(h.y, w1.w, acc[kk][3]);
                acc[kk][3] = fmaf(h.z, w2.w, acc[kk][3]);
                acc[kk][3] = fmaf(h.w, w3.w, acc[kk][3]);
            }
        }
        __shared__ float pm2[4][C2];
        float m0 = NEGV, m1 = NEGV, m2 = NEGV, m3 = NEGV;
#pragma unroll
        for (int kk = 0; kk < K / 4; ++kk) {
            if (s_valid[k0 + kk]) {         // wave-uniform branch
                m0 = fmaxf(m0, fmaxf(acc[kk][0], 0.f));
                m1 = fmaxf(m1, fmaxf(acc[kk][1], 0.f));
                m2 = fmaxf(m2, fmaxf(acc[kk][2], 0.f));
                m3 = fmaxf(m3, fmaxf(acc[kk][3], 0.f));
            }
        }
        float4 mv; mv.x = m0; mv.y = m1; mv.z = m2; mv.w = m3;
        *(float4*)&pm2[wv_][j0] = mv;
        __syncthreads();
        float r = fmaxf(fmaxf(pm2[0][t], pm2[1][t]),
                        fmaxf(pm2[2][t], pm2[3][t]));
        out[c * 384 + OUTOFF + t] = r;
    } else {
        // C2 == 128: 2 thread-groups split the k range, combine via LDS
        const int j2 = t % C2;
        const int g  = t / C2;
        __shared__ float pm[256];
        float w2c[C1];
#pragma unroll
        for (int i = 0; i < C1; ++i) w2c[i] = W2[i * C2 + j2];
        const float bj = B2[j2];
        float omax = NEGV;
        for (int k = g; k < K; k += 2) {
            if (!s_valid[k]) continue;
            float acc = bj;
            const float4* hr = (const float4*)&H[k][0];
#pragma unroll
            for (int q = 0; q < C1 / 4; ++q) {
                float4 h = hr[q];
                acc = fmaf(h.x, w2c[4 * q + 0], acc);
                acc = fmaf(h.y, w2c[4 * q + 1], acc);
                acc = fmaf(h.z, w2c[4 * q + 2], acc);
                acc = fmaf(h.w, w2c[4 * q + 3], acc);
            }
            omax = fmaxf(omax, fmaxf(acc, 0.f));
        }
        pm[t] = omax;
        __syncthreads();
        if (t < C2) out[c * 384 + OUTOFF + t] = fmaxf(pm[t], pm[t + C2]);
    }
}

extern "C" void kernel_launch(void* const* d_in, const int* in_sizes, int n_in,
                              void* d_out, int out_size, void* d_ws, size_t ws_size,
                              hipStream_t stream) {
    const float* x    = (const float*)d_in[0];
    const float* pos  = (const float*)d_in[1];
    const float* w1_0 = (const float*)d_in[2];
    const float* b1_0 = (const float*)d_in[3];
    const float* w1_1 = (const float*)d_in[4];
    const float* b1_1 = (const float*)d_in[5];
    const float* w2_0 = (const float*)d_in[6];
    const float* b2_0 = (const float*)d_in[7];
    const float* w2_1 = (const float*)d_in[8];
    const float* b2_1 = (const float*)d_in[9];

    float* out   = (float*)d_out;
    float* pos_s = out + NCENT * 384;          // second output, written by FPS

    char* ws = (char*)d_ws;
    int*   ncnt = (int*)ws;                                   // NCENT ints
    int*   nidx = (int*)(ws + NCENT * 4);                     // NCENT*64 ints
    float* nd2  = (float*)(ws + NCENT * 4 + NCENT * KMAX * 4);// NCENT*64 floats

    fps_kernel<<<BATCH, FPS_T, 0, stream>>>(pos, pos_s);
    knn_kernel<<<NCENT, 256, 0, stream>>>(pos, pos_s, nidx, nd2, ncnt);
    mlp_kernel<32, 64, 128, 0><<<NCENT, 256, 0, stream>>>(
        x, pos, pos_s, nidx, nd2, ncnt, w1_0, b1_0, w1_1, b1_1, out, 0.04f);
    mlp_kernel<64, 128, 256, 128><<<NCENT, 256, 0, stream>>>(
        x, pos, pos_s, nidx, nd2, ncnt, w2_0, b2_0, w2_1, b2_1, out, 0.16f);
}

// Round 6
// 2649.512 us; speedup vs baseline: 1.1465x; 1.1206x over previous
//
#include <hip/hip_runtime.h>
#include <stdint.h>

#define BATCH 4
#define NPTS  8192
#define CFEAT 64
#define MCENT 2048
#define NCENT (BATCH * MCENT)
#define KMAX  64
#define NEGV  -1e30f

// Exact-rounding squared distance, matching numpy's ((dx*dx+dy*dy)+dz*dz)
// with NO fma contraction (discrete neighbor selection requires bit parity).
__device__ __forceinline__ float dist2(float ax, float ay, float az,
                                       float bx, float by, float bz) {
    float dx = __fsub_rn(ax, bx);
    float dy = __fsub_rn(ay, by);
    float dz = __fsub_rn(az, bz);
    return __fadd_rn(__fadd_rn(__fmul_rn(dx, dx), __fmul_rn(dy, dy)),
                     __fmul_rn(dz, dz));
}

template <int CTRL>
__device__ __forceinline__ int dppi(int v) {
    return __builtin_amdgcn_update_dpp(v, v, CTRL, 0xF, 0xF, false);
}

// u64 max-combine with a DPP lane permute (lo/hi words permuted separately).
#define KSTEP(k, C_) { int klo_ = dppi<C_>((int)(unsigned int)(k));           \
                       int khi_ = dppi<C_>((int)(unsigned int)((k) >> 32));   \
                       unsigned long long ok_ =                               \
                           ((unsigned long long)(unsigned int)khi_ << 32) |   \
                           (unsigned int)klo_;                                \
                       (k) = ok_ > (k) ? ok_ : (k); }

// ---------------------------------------------------------------------------
// Kernel 1: farthest point sampling — r3 configuration VERBATIM (measured
// 1822us, the best of 5 attempts).
// Post-mortem ledger: r0 remat-reload 2860; r1 LDS-read/iter 2899; r2 global
// spin 8500+; r3 reg-pin single-barrier 1822; r4 256t latency-exposed 2004;
// r5 float-tail but TWO barriers 1956. The serial tail (barrier + ds_read
// ~120cy + chain + bcast read) is latency-bound — a second barrier costs
// more than ~600cy of saved issue. Single barrier + u64 key wins.
// ---------------------------------------------------------------------------
#define FPS_T   512
#define FPS_W   (FPS_T / 64)

#define REP16(X) X(0) X(1) X(2) X(3) X(4) X(5) X(6) X(7) \
                 X(8) X(9) X(10) X(11) X(12) X(13) X(14) X(15)

__global__ __launch_bounds__(FPS_T, 2) void fps_kernel(const float* __restrict__ pos,
                                                       float* __restrict__ pos_s) {
    const int b = blockIdx.x;
    const float* pb = pos + b * NPTS * 3;
    const int t = threadIdx.x;          // 0..511
    const int w = t >> 6;               // wave id 0..7
    const int lane = t & 63;

    __shared__ float2 sxy[NPTS];        // 64 KB (winner broadcast + writeback)
    __shared__ float  sz[NPTS];         // 32 KB
    __shared__ unsigned long long s_key[2][FPS_W];
    __shared__ int    s_win[MCENT];     // 8 KB winner indices

#define FPS_DECL(i) float px##i, py##i, pz##i, mind##i;
    REP16(FPS_DECL)
#undef FPS_DECL

    // load each point once: into pinned registers AND the LDS copy
#define FPS_LOAD(i) { int p = (i << 9) + t;                                   \
                      px##i = pb[3 * p + 0];                                  \
                      py##i = pb[3 * p + 1];                                  \
                      pz##i = pb[3 * p + 2];                                  \
                      float2 xy_; xy_.x = px##i; xy_.y = py##i;               \
                      sxy[p] = xy_;  sz[p] = pz##i;                           \
                      mind##i = 1e30f;                                        \
                      asm volatile("" : "+v"(px##i), "+v"(py##i), "+v"(pz##i)); }
    REP16(FPS_LOAD)
#undef FPS_LOAD

    if (t == 0) s_win[0] = 0;           // first centroid = point 0
    __syncthreads();

    float lx = sxy[0].x, ly = sxy[0].y, lz = sz[0];

    for (int m = 0; m < MCENT - 1; ++m) {
        // update mind, thread-local argmax over the 16 slots (i ascending ==
        // point index ascending for fixed t; strict > keeps lowest index).
        float bv = -1.0f; int bi = 0;
#define FPS_UPD(i) { float d = dist2(px##i, py##i, pz##i, lx, ly, lz);        \
                     float mn = fminf(mind##i, d);                            \
                     mind##i = mn;                                            \
                     bool tk = mn > bv;                                       \
                     bv = tk ? mn : bv;                                       \
                     bi = tk ? i : bi; }
        REP16(FPS_UPD)
#undef FPS_UPD
        int bp = (bi << 9) + t;

        // pack (d2, min-index) into one u64: bits monotone for nonneg floats,
        // invp tie-break -> min global index.
        unsigned long long key =
            ((unsigned long long)__float_as_uint(bv) << 13) |
            (unsigned int)(8191 - bp);

        // wave reduce to lane 63 (absorb chain, idempotent u64 max)
        KSTEP(key, 0xB1)    // quad_perm xor1
        KSTEP(key, 0x4E)    // quad_perm xor2
        KSTEP(key, 0x141)   // row_half_mirror
        KSTEP(key, 0x140)   // row_mirror
        KSTEP(key, 0x142)   // row_bcast15
        KSTEP(key, 0x143)   // row_bcast31 -> lane63 holds wave winner

        const int par = m & 1;
        if (lane == 63) s_key[par][w] = key;
        __syncthreads();

        // every thread: one b64 read of slot (t&7), then 3-step butterfly.
        unsigned long long k = s_key[par][t & 7];
        KSTEP(k, 0xB1)
        KSTEP(k, 0x4E)
        KSTEP(k, 0x141)

        int gp = 8191 - (int)(k & 0x1FFFULL);
        if (t == 0) s_win[m + 1] = gp;
        float2 cxy = sxy[gp];            // broadcast LDS read (same addr)
        lx = cxy.x; ly = cxy.y; lz = sz[gp];
    }

    // bulk pos_s writeback (the only global stores in the kernel)
    __syncthreads();
    for (int m = t; m < MCENT; m += FPS_T) {
        int gp = s_win[m];
        float2 xy = sxy[gp]; float z = sz[gp];
        float* o = pos_s + (b * MCENT + m) * 3;
        o[0] = xy.x; o[1] = xy.y; o[2] = z;
    }
}
#undef KSTEP

// ---------------------------------------------------------------------------
// Kernel 2: exact top-64 (by (d2, idx) u64 key) within ball r=0.4 via
// histogram radix-select + O(C^2) exact ranking. Unchanged.
// ---------------------------------------------------------------------------
#define KNN_CAP 320

__global__ __launch_bounds__(256) void knn_kernel(const float* __restrict__ pos,
                                                  const float* __restrict__ pos_s,
                                                  int* __restrict__ nidx,
                                                  float* __restrict__ nd2,
                                                  int* __restrict__ ncnt) {
    const int c = blockIdx.x;
    const int b = c >> 11;              // c / MCENT
    const float* pb = pos + b * NPTS * 3;
    const int t = threadIdx.x;

    const float cx = pos_s[c * 3 + 0];
    const float cy = pos_s[c * 3 + 1];
    const float cz = pos_s[c * 3 + 2];

    __shared__ int hist[64];
    __shared__ int s_B64, s_total, s_cnt;
    __shared__ unsigned long long cand[KNN_CAP];

    if (t < 64) hist[t] = 0;
    if (t == 0) s_cnt = 0;
    __syncthreads();

    float d2r[32];
#pragma unroll
    for (int i = 0; i < 32; ++i) {
        int p = (i << 8) + t;
        float d2 = dist2(cx, cy, cz, pb[3 * p + 0], pb[3 * p + 1], pb[3 * p + 2]);
        d2r[i] = d2;
        if (d2 <= 0.16f) {
            int bkt = (int)(d2 * 400.0f);      // monotone; 0.16f*400 < 64
            bkt = bkt > 63 ? 63 : bkt;
            atomicAdd(&hist[bkt], 1);
        }
    }
    __syncthreads();

    if (t == 0) {
        int cum = 0, B = -1;
#pragma unroll
        for (int j = 0; j < 64; ++j) {
            cum += hist[j];
            if (B < 0 && cum >= 64) B = j;
        }
        s_B64 = (B < 0) ? 63 : B;
        s_total = cum;
    }
    __syncthreads();

    const int B64 = s_B64;
#pragma unroll
    for (int i = 0; i < 32; ++i) {
        float d2 = d2r[i];
        if (d2 <= 0.16f) {
            int bkt = (int)(d2 * 400.0f);
            bkt = bkt > 63 ? 63 : bkt;
            if (bkt <= B64) {
                int slot = atomicAdd(&s_cnt, 1);
                if (slot < KNN_CAP) {
                    int p = (i << 8) + t;
                    cand[slot] = ((unsigned long long)__float_as_uint(d2) << 32)
                                 | (unsigned int)p;
                }
            }
        }
    }
    __syncthreads();

    const int C = s_cnt < KNN_CAP ? s_cnt : KNN_CAP;
    for (int tc = t; tc < C; tc += 256) {
        unsigned long long my = cand[tc];
        int rank = 0;
        for (int j = 0; j < C; ++j) rank += (cand[j] < my) ? 1 : 0;
        if (rank < KMAX) {
            nidx[c * KMAX + rank] = (int)(my & 0xffffffffULL);
            nd2[c * KMAX + rank]  = __uint_as_float((unsigned int)(my >> 32));
        }
    }
    if (t == 0) ncnt[c] = s_total < KMAX ? s_total : KMAX;
}

// ---------------------------------------------------------------------------
// Kernel 3: fused MLP + masked max per centroid.
//
// Round-6 L1 rewrite: the gather phase (per-wave ~4 distinct x-rows ->
// ~20 cache requests per instruction, 1088 insts/block) and the F LDS
// round-trip (write 17KB + 544 bcast b128 reads/wave) are replaced by
// DIRECT broadcast x reads in a register-tiled L1: half-wave owns K/8
// k-rows, lane owns C1/32 j-cols; x row chunks read with uniform address
// (1-2 requests/inst); pos-delta row from a tiny LDS float4 array.
// Bit-exact: per-(k,j) op order unchanged (bias first, i=0..67 ascending
// fmaf, zero-pad x 0). Invalid k produce garbage-but-finite H, excluded by
// s_valid exactly as before. L2 paths unchanged (r4 structure).
// ---------------------------------------------------------------------------
template <int K, int C1, int C2, int OUTOFF>
__global__ __launch_bounds__(256, 2) void mlp_kernel(
        const float* __restrict__ x, const float* __restrict__ pos,
        const float* __restrict__ pos_s,
        const int* __restrict__ nidx, const float* __restrict__ nd2,
        const int* __restrict__ ncnt,
        const float* __restrict__ W1, const float* __restrict__ B1,
        const float* __restrict__ W2, const float* __restrict__ B2,
        float* __restrict__ out, float r2) {
    const int c = blockIdx.x;
    const int b = c >> 11;
    const int t = threadIdx.x;

    constexpr int HK  = K / 8;      // k-rows per half-wave
    constexpr int NJ1 = C1 / 32;    // j-cols per lane in L1 (4 or 2)

    __shared__ float  H[K][C1];
    __shared__ float4 s_p3[K];      // [pos[nbr]-ctr, 0]
    __shared__ int    s_nbr[K];
    __shared__ int    s_valid[K];

    const int cntAll = ncnt[c];
    const int cnt = cntAll < K ? cntAll : K;
    if (t < K) {
        bool ok = t < cnt;
        int nbr = ok ? nidx[c * KMAX + t] : 0;
        s_nbr[t]   = nbr;
        s_valid[t] = ok && (nd2[c * KMAX + t] <= r2);
        const float* pp = pos + (b * NPTS + nbr) * 3;
        float4 p;
        p.x = pp[0] - pos_s[c * 3 + 0];
        p.y = pp[1] - pos_s[c * 3 + 1];
        p.z = pp[2] - pos_s[c * 3 + 2];
        p.w = 0.f;
        s_p3[t] = p;
    }
    __syncthreads();

    // ---- layer 1: register-tiled, x read directly with broadcast addrs ----
    {
        const int wv = t >> 6;
        const int hf = (t & 63) >> 5;
        const int sl = t & 31;
        const int k0 = wv * (K / 4) + hf * HK;
        const int j0 = sl * NJ1;

        int xo[HK];
#pragma unroll
        for (int kk = 0; kk < HK; ++kk)
            xo[kk] = (b * NPTS + s_nbr[k0 + kk]) * CFEAT;

        float acc[HK][NJ1];
#pragma unroll
        for (int kk = 0; kk < HK; ++kk)
#pragma unroll
            for (int j = 0; j < NJ1; ++j) acc[kk][j] = B1[j0 + j];

#pragma unroll 4
        for (int q = 0; q < 16; ++q) {          // rows 4q..4q+3, all < 64
            float wr[4][NJ1];
#pragma unroll
            for (int r = 0; r < 4; ++r)
#pragma unroll
                for (int j = 0; j < NJ1; ++j)
                    wr[r][j] = W1[(4 * q + r) * C1 + j0 + j];
#pragma unroll
            for (int kk = 0; kk < HK; ++kk) {
                float4 h = *(const float4*)(x + xo[kk] + 4 * q);
#pragma unroll
                for (int j = 0; j < NJ1; ++j) {
                    float a = acc[kk][j];
                    a = fmaf(h.x, wr[0][j], a);
                    a = fmaf(h.y, wr[1][j], a);
                    a = fmaf(h.z, wr[2][j], a);
                    a = fmaf(h.w, wr[3][j], a);
                    acc[kk][j] = a;
                }
            }
        }
        {   // tail: rows 64,65,66 (pos-delta) + zero row 67
            float wr[4][NJ1];
#pragma unroll
            for (int r = 0; r < 3; ++r)
#pragma unroll
                for (int j = 0; j < NJ1; ++j)
                    wr[r][j] = W1[(64 + r) * C1 + j0 + j];
#pragma unroll
            for (int j = 0; j < NJ1; ++j) wr[3][j] = 0.f;
#pragma unroll
            for (int kk = 0; kk < HK; ++kk) {
                float4 h = s_p3[k0 + kk];       // h.w == 0
#pragma unroll
                for (int j = 0; j < NJ1; ++j) {
                    float a = acc[kk][j];
                    a = fmaf(h.x, wr[0][j], a);
                    a = fmaf(h.y, wr[1][j], a);
                    a = fmaf(h.z, wr[2][j], a);
                    a = fmaf(h.w, wr[3][j], a);
                    acc[kk][j] = a;
                }
            }
        }
#pragma unroll
        for (int kk = 0; kk < HK; ++kk)
#pragma unroll
            for (int j = 0; j < NJ1; ++j)
                H[k0 + kk][j0 + j] = fmaxf(acc[kk][j], 0.f);
    }
    __syncthreads();

    // ---- layer 2 + masked max over neighbors (r4 structure, unchanged) ----
    if constexpr (C2 == 256) {
        // k-split across waves; 4 j columns per lane; acc in registers.
        const int lane_ = t & 63;
        const int wv_   = t >> 6;           // 0..3
        const int j0    = lane_ * 4;
        const int k0    = wv_ * (K / 4);    // 16 k-rows per wave
        float4 bjv = *(const float4*)&B2[j0];
        float acc[K / 4][4];
#pragma unroll
        for (int kk = 0; kk < K / 4; ++kk) {
            acc[kk][0] = bjv.x; acc[kk][1] = bjv.y;
            acc[kk][2] = bjv.z; acc[kk][3] = bjv.w;
        }
        for (int i = 0; i < C1; i += 4) {
            float4 w0 = *(const float4*)&W2[(i + 0) * C2 + j0];
            float4 w1 = *(const float4*)&W2[(i + 1) * C2 + j0];
            float4 w2 = *(const float4*)&W2[(i + 2) * C2 + j0];
            float4 w3 = *(const float4*)&W2[(i + 3) * C2 + j0];
#pragma unroll
            for (int kk = 0; kk < K / 4; ++kk) {
                float4 h = *(const float4*)&H[k0 + kk][i];   // broadcast
                acc[kk][0] = fmaf(h.x, w0.x, acc[kk][0]);
                acc[kk][0] = fmaf(h.y, w1.x, acc[kk][0]);
                acc[kk][0] = fmaf(h.z, w2.x, acc[kk][0]);
                acc[kk][0] = fmaf(h.w, w3.x, acc[kk][0]);
                acc[kk][1] = fmaf(h.x, w0.y, acc[kk][1]);
                acc[kk][1] = fmaf(h.y, w1.y, acc[kk][1]);
                acc[kk][1] = fmaf(h.z, w2.y, acc[kk][1]);
                acc[kk][1] = fmaf(h.w, w3.y, acc[kk][1]);
                acc[kk][2] = fmaf(h.x, w0.z, acc[kk][2]);
                acc[kk][2] = fmaf(h.y, w1.z, acc[kk][2]);
                acc[kk][2] = fmaf(h.z, w2.z, acc[kk][2]);
                acc[kk][2] = fmaf(h.w, w3.z, acc[kk][2]);
                acc[kk][3] = fmaf(h.x, w0.w, acc[kk][3]);
                acc[kk][3] = fmaf(h.y, w1.w, acc[kk][3]);
                acc[kk][3] = fmaf(h.z, w2.w, acc[kk][3]);
                acc[kk][3] = fmaf(h.w, w3.w, acc[kk][3]);
            }
        }
        __shared__ float pm2[4][C2];
        float m0 = NEGV, m1 = NEGV, m2 = NEGV, m3 = NEGV;
#pragma unroll
        for (int kk = 0; kk < K / 4; ++kk) {
            if (s_valid[k0 + kk]) {         // wave-uniform branch
                m0 = fmaxf(m0, fmaxf(acc[kk][0], 0.f));
                m1 = fmaxf(m1, fmaxf(acc[kk][1], 0.f));
                m2 = fmaxf(m2, fmaxf(acc[kk][2], 0.f));
                m3 = fmaxf(m3, fmaxf(acc[kk][3], 0.f));
            }
        }
        float4 mv; mv.x = m0; mv.y = m1; mv.z = m2; mv.w = m3;
        *(float4*)&pm2[wv_][j0] = mv;
        __syncthreads();
        float r = fmaxf(fmaxf(pm2[0][t], pm2[1][t]),
                        fmaxf(pm2[2][t], pm2[3][t]));
        out[c * 384 + OUTOFF + t] = r;
    } else {
        // C2 == 128: 2 thread-groups split the k range, combine via LDS
        const int j2 = t % C2;
        const int g  = t / C2;
        __shared__ float pm[256];
        float w2c[C1];
#pragma unroll
        for (int i = 0; i < C1; ++i) w2c[i] = W2[i * C2 + j2];
        const float bj = B2[j2];
        float omax = NEGV;
        for (int k = g; k < K; k += 2) {
            if (!s_valid[k]) continue;
            float acc = bj;
            const float4* hr = (const float4*)&H[k][0];
#pragma unroll
            for (int q = 0; q < C1 / 4; ++q) {
                float4 h = hr[q];
                acc = fmaf(h.x, w2c[4 * q + 0], acc);
                acc = fmaf(h.y, w2c[4 * q + 1], acc);
                acc = fmaf(h.z, w2c[4 * q + 2], acc);
                acc = fmaf(h.w, w2c[4 * q + 3], acc);
            }
            omax = fmaxf(omax, fmaxf(acc, 0.f));
        }
        pm[t] = omax;
        __syncthreads();
        if (t < C2) out[c * 384 + OUTOFF + t] = fmaxf(pm[t], pm[t + C2]);
    }
}

extern "C" void kernel_launch(void* const* d_in, const int* in_sizes, int n_in,
                              void* d_out, int out_size, void* d_ws, size_t ws_size,
                              hipStream_t stream) {
    const float* x    = (const float*)d_in[0];
    const float* pos  = (const float*)d_in[1];
    const float* w1_0 = (const float*)d_in[2];
    const float* b1_0 = (const float*)d_in[3];
    const float* w1_1 = (const float*)d_in[4];
    const float* b1_1 = (const float*)d_in[5];
    const float* w2_0 = (const float*)d_in[6];
    const float* b2_0 = (const float*)d_in[7];
    const float* w2_1 = (const float*)d_in[8];
    const float* b2_1 = (const float*)d_in[9];

    float* out   = (float*)d_out;
    float* pos_s = out + NCENT * 384;          // second output, written by FPS

    char* ws = (char*)d_ws;
    int*   ncnt = (int*)ws;                                   // NCENT ints
    int*   nidx = (int*)(ws + NCENT * 4);                     // NCENT*64 ints
    float* nd2  = (float*)(ws + NCENT * 4 + NCENT * KMAX * 4);// NCENT*64 floats

    fps_kernel<<<BATCH, FPS_T, 0, stream>>>(pos, pos_s);
    knn_kernel<<<NCENT, 256, 0, stream>>>(pos, pos_s, nidx, nd2, ncnt);
    mlp_kernel<32, 64, 128, 0><<<NCENT, 256, 0, stream>>>(
        x, pos, pos_s, nidx, nd2, ncnt, w1_0, b1_0, w1_1, b1_1, out, 0.04f);
    mlp_kernel<64, 128, 256, 128><<<NCENT, 256, 0, stream>>>(
        x, pos, pos_s, nidx, nd2, ncnt, w2_0, b2_0, w2_1, b2_1, out, 0.16f);
}